// Round 17
// baseline (136.564 us; speedup 1.0000x reference)
//
#include <hip/hip_runtime.h>
#include <cstddef>

#define NBATCH 4096
#define NTIME  64
#define NDIM   16
#define NLDIM  64
#define NAUXK  32
#define NAH    128
#define NH     256
#define MROWS  (NBATCH*NTIME)   // 262144
#define DT_C   0.01f
#define EPS_C  1e-5f
#define ENC_BLOCKS (MROWS/64)              // 4096
#define AUX_BLOCKS (NAUXK*64)              // 2048
#define ESTR 264     // enc h stride (ushorts): 528B = 16 mod 128 -> bank-slot drift
#define ASTR 136     // aux h stride: 272B = 16 mod 128

using short8 = __attribute__((ext_vector_type(8))) short;
using short4v = __attribute__((ext_vector_type(4))) short;
using f32x4 = __attribute__((ext_vector_type(4))) float;

__device__ __forceinline__ float lrelu(float x){ return fmaxf(x, 0.01f*x); }
__device__ __forceinline__ unsigned short f2bf(float f){
    unsigned u = __builtin_bit_cast(unsigned, f);
    u += 0x7fff + ((u>>16)&1u);
    return (unsigned short)(u>>16);
}
// HW packed cvt: low16=bf16(a), high16=bf16(b), RNE
__device__ __forceinline__ unsigned cvt_pk(float a, float b){
    unsigned r;
    asm("v_cvt_pk_bf16_f32 %0, %1, %2" : "=v"(r) : "v"(a), "v"(b));
    return r;
}
__device__ __forceinline__ short4v pack4(f32x4 a){
    uint2 u;
    u.x = cvt_pk(lrelu(a[0]), lrelu(a[1]));
    u.y = cvt_pk(lrelu(a[2]), lrelu(a[3]));
    return __builtin_bit_cast(short4v, u);
}

// padded-linear LDS access: no swizzle, b128 reads, b64 writes
template<int STRIDE>
__device__ __forceinline__ short8 ld_h(const unsigned short* hb, int m, int c){
    return *(const short8*)&hb[m*STRIDE + c];
}
template<int STRIDE>
__device__ __forceinline__ void st_h(unsigned short* hb, int m, int c, short4v p){
    *(short4v*)&hb[m*STRIDE + c] = p;
}

// ================= Mega-kernel 1: prep + auxb fold + all partial stats =========
// blocks [0,2896): weight prep; [2896,2912): aux b1 fold;
// [2912,3936): enc BN partial stats (1024 blocks); [3936,3952): x0 partials.
__global__ __launch_bounds__(256) void k_mega1(const float* __restrict__ W1,
                                               const float* __restrict__ W2,
                                               const float* __restrict__ W3,
                                               const float* __restrict__ esc,
                                               const float* __restrict__ ag,
                                               const float* __restrict__ aW1,
                                               const float* __restrict__ aW2,
                                               const float* __restrict__ aW3,
                                               const float* __restrict__ asc,
                                               const float* __restrict__ ab1,
                                               const float* __restrict__ abt,
                                               const float* __restrict__ xs,
                                               unsigned short* __restrict__ dst,
                                               float* __restrict__ b1p,
                                               float* __restrict__ part,
                                               float* __restrict__ part2){
    __shared__ float red[256*33];
    const int blk = blockIdx.x;
    const int tid = threadIdx.x;

    if(blk < 2896){
        int i = blk*256 + tid;
        float v;
        if(i < 4096){ v = W1[i]; }
        else if(i < 69632){
            int e = i - 4096;
            int kt = e>>13, r = e&8191;
            int rb = r>>9, sft = r&511;
            int l = sft>>3, j = sft&7;
            int g = l>>4, arw = l&15;
            v = W2[(rb*16+arw)*256 + kt*32 + g*8 + j];
        } else if(i < 86016){
            int e = i - 69632;
            int kt = e>>11, r = e&2047;
            int rb = r>>9, sft = r&511;
            int l = sft>>3, j = sft&7;
            int g = l>>4, arw = l&15;
            int n = rb*16 + arw;
            v = W3[n*256 + kt*32 + g*8 + j] * esc[n];       // esc folded in
        } else if(i < 151552){
            int e = i - 86016; int k = e>>11, n = (e>>4)&127, c = e&15;
            v = aW1[(k*128+n)*16 + c] * ag[k*16+c];
        } else if(i < 675840){
            int e = i - 151552; int k = e>>14, kt = (e>>12)&3, n = (e>>5)&127, j = e&31;
            v = aW2[(k*128+n)*128 + kt*32 + j];
        } else if(i < 741376){
            int e = i - 675840; int k = e>>11, kt = (e>>9)&3, n = (e>>5)&15, j = e&31;
            v = (n < 2) ? aW3[(k*2+n)*128 + kt*32 + j] * asc[k*2+n] * DT_C : 0.f;  // asc*DT folded
        } else return;
        dst[i] = f2bf(v);
    } else if(blk < 2912){
        int i = (blk-2896)*256 + tid;
        int k = i>>7, n = i&127;
        const float* wr = aW1 + (size_t)(k*128+n)*16;
        const float* bt = abt + k*16;
        float a = ab1[i];
#pragma unroll
        for(int c=0;c<16;c++) a += wr[c]*bt[c];
        b1p[i] = a;
    } else if(blk < 3936){
        int sblk = blk - 2912;
        int r0 = sblk*256 + tid;
        const float4* p = (const float4*)(xs + (size_t)r0*NDIM);
        float s[16], q[16];
#pragma unroll
        for(int v=0; v<4; v++){
            float4 f = p[v];
            s[v*4+0]=f.x; q[v*4+0]=f.x*f.x;
            s[v*4+1]=f.y; q[v*4+1]=f.y*f.y;
            s[v*4+2]=f.z; q[v*4+2]=f.z*f.z;
            s[v*4+3]=f.w; q[v*4+3]=f.w*f.w;
        }
#pragma unroll
        for(int i=0;i<16;i++){ red[tid*33+i]=s[i]; red[tid*33+16+i]=q[i]; }
        __syncthreads();
        for(int off=128; off>0; off>>=1){
            if(tid < off){
#pragma unroll
                for(int i=0;i<32;i++) red[tid*33+i] += red[(tid+off)*33+i];
            }
            __syncthreads();
        }
        if(tid < 32) part[sblk*32 + tid] = red[tid];
    } else {
        int sblk = blk - 3936;
        int b = sblk*256 + tid;
        const float4* p = (const float4*)(xs + (size_t)b*(NTIME*NDIM));
#pragma unroll
        for(int v=0; v<4; v++){
            float4 f = p[v];
            red[tid*33 + v*4+0] = f.x; red[tid*33+16 + v*4+0] = f.x*f.x;
            red[tid*33 + v*4+1] = f.y; red[tid*33+16 + v*4+1] = f.y*f.y;
            red[tid*33 + v*4+2] = f.z; red[tid*33+16 + v*4+2] = f.z*f.z;
            red[tid*33 + v*4+3] = f.w; red[tid*33+16 + v*4+3] = f.w*f.w;
        }
        __syncthreads();
        for(int off=128; off>0; off>>=1){
            if(tid < off){
#pragma unroll
                for(int i=0;i<32;i++) red[tid*33+i] += red[(tid+off)*33+i];
            }
            __syncthreads();
        }
        if(tid < 32) part2[sblk*32 + tid] = red[tid];
    }
}

// ---------------- Kernel 2: finalize stats (pure reduction) --------------------
// stats layout: [0:16]=a_enc, [16:32]=b_enc, [32:48]=m0, [48:64]=istd0
__global__ __launch_bounds__(256) void k_finalize(const float* __restrict__ part,
                                                  const float* __restrict__ part2,
                                                  const float* __restrict__ gamma,
                                                  const float* __restrict__ beta,
                                                  float* __restrict__ stats){
    __shared__ float red[256*33];
    __shared__ float x0tot[32];
    int tid = threadIdx.x;
#pragma unroll
    for(int i=0;i<32;i++) red[tid*33+i] = (tid < 16) ? part2[tid*32+i] : 0.f;
    __syncthreads();
    for(int off=8; off>0; off>>=1){
        if(tid < off){
#pragma unroll
            for(int i=0;i<32;i++) red[tid*33+i] += red[(tid+off)*33+i];
        }
        __syncthreads();
    }
    if(tid < 32) x0tot[tid] = red[tid];
    __syncthreads();
#pragma unroll
    for(int i=0;i<32;i++){
        float a = part[tid*32+i] + part[(tid+256)*32+i]
                + part[(tid+512)*32+i] + part[(tid+768)*32+i];
        red[tid*33+i] = a;
    }
    __syncthreads();
    for(int off=128; off>0; off>>=1){
        if(tid < off){
#pragma unroll
            for(int i=0;i<32;i++) red[tid*33+i] += red[(tid+off)*33+i];
        }
        __syncthreads();
    }
    if(tid < 16){
        int i = tid;
        float m0 = x0tot[i] / (float)NBATCH;
        float v0 = x0tot[16+i] / (float)NBATCH - m0*m0;
        stats[32+i] = m0;
        stats[48+i] = 1.0f / sqrtf(v0 + EPS_C);
        float me = red[i] / (float)MROWS;
        float ve = red[16+i] / (float)MROWS - me*me;
        float a = gamma[i] / sqrtf(ve + EPS_C);
        stats[i]      = a;
        stats[16+i]   = beta[i] - me*a;
    }
}

// ---------------- enc path: 8 waves, wave w owns cols [w*32,w*32+32) -----------
__device__ __forceinline__ void enc_body(unsigned short* smem, int eb, int tid,
                                         const float* __restrict__ xs,
                                         const float* __restrict__ stats,
                                         const unsigned short* __restrict__ W1bf,
                                         const float* __restrict__ b1,
                                         const unsigned short* __restrict__ W2s,
                                         const float* __restrict__ b2,
                                         const unsigned short* __restrict__ W3s,
                                         float* __restrict__ outy){
    unsigned short* xa = smem;          // 1024 ushorts
    unsigned short* hb = smem + 1024;   // 64*ESTR ushorts, padded-linear

    const int w    = tid >> 6;          // 0..7
    const int lane = tid & 63;
    const int g    = lane >> 4;
    const int arow = lane & 15;
    const int mh   = w & 1;             // layer-3 row-half
    const int nt3  = w >> 1;            // layer-3 col-tile

    const int c2  = (tid & 7)*2;
    const int r0p = tid >> 3;
    const float sa0 = stats[c2],    sa1 = stats[c2+1];
    const float sb0 = stats[16+c2], sb1 = stats[16+c2+1];

    const unsigned short* w2base = W2s + (w*2)*512 + lane*8;  // rb = w*2+nt
    const unsigned short* w3base = W3s + nt3*512 + lane*8;    // rb = nt3

    const int m0 = eb*64;

    // prefetch W2 kt=0 into buffer A (hidden under phase0 + layer1)
    short8 bA0 = *(const short8*)&w2base[0];
    short8 bA1 = *(const short8*)&w2base[512];

    // ---- phase 0: 64 rows, passthrough + BN->bf16 (float2/thread) ---------
    {
        float2 v = *(const float2*)(xs + (size_t)(m0 + r0p)*NDIM + c2);
        *(float2*)(outy + (size_t)(m0 + r0p)*80 + c2) = v;
        unsigned u = cvt_pk(v.x*sa0 + sb0, v.y*sa1 + sb1);
        *(unsigned*)&xa[r0p*16 + c2] = u;
    }
    __syncthreads();

    // ---- layer 1: K=16; bias in MFMA C operand ----------------------------
#pragma unroll
    for(int nt=0; nt<2; nt++){
        short8 aw = {0,0,0,0,0,0,0,0};
        if(lane < 32) aw = *(const short8*)&W1bf[(w*32 + nt*16 + arow)*16 + g*8];
        float4 b4 = *(const float4*)&b1[w*32 + nt*16 + g*4];
        f32x4 bi = {b4.x, b4.y, b4.z, b4.w};
#pragma unroll
        for(int mt=0; mt<4; mt++){
            short8 bx = {0,0,0,0,0,0,0,0};
            if(lane < 32) bx = *(const short8*)&xa[(mt*16 + arow)*16 + g*8];
            f32x4 a = __builtin_amdgcn_mfma_f32_16x16x32_bf16(aw, bx, bi, 0, 0, 0);
            st_h<ESTR>(hb, mt*16 + arow, w*32 + nt*16 + g*4, pack4(a));
        }
    }
    __syncthreads();

    // ---- layer 2: K=256, A/B W2 buffers + rotated bh refill ----------------
    f32x4 acc[2][4];
#pragma unroll
    for(int nt=0; nt<2; nt++){
        float4 b4 = *(const float4*)&b2[w*32 + nt*16 + g*4];
        f32x4 bi = {b4.x, b4.y, b4.z, b4.w};
#pragma unroll
        for(int m=0;m<4;m++) acc[nt][m] = bi;
    }

    short8 bh[4];
#pragma unroll
    for(int mt=0; mt<4; mt++) bh[mt] = ld_h<ESTR>(hb, mt*16 + arow, g*8);

#pragma unroll 1
    for(int i2=0; i2<4; i2++){
        const int kt0 = i2*2, kt1 = i2*2+1;
        const unsigned short* wp1 = w2base + kt1*8192;
        short8 bB0 = *(const short8*)&wp1[0];
        short8 bB1 = *(const short8*)&wp1[512];
        __builtin_amdgcn_s_setprio(1);
#pragma unroll
        for(int mt=0; mt<4; mt++){
            short8 b = bh[mt];
            acc[0][mt] = __builtin_amdgcn_mfma_f32_16x16x32_bf16(bA0, b, acc[0][mt], 0, 0, 0);
            acc[1][mt] = __builtin_amdgcn_mfma_f32_16x16x32_bf16(bA1, b, acc[1][mt], 0, 0, 0);
            bh[mt] = ld_h<ESTR>(hb, mt*16 + arow, kt1*32 + g*8);   // refill for kt1
        }
        __builtin_amdgcn_s_setprio(0);
        if(i2 < 3){
            const unsigned short* wp2 = w2base + (kt0+2)*8192;
            bA0 = *(const short8*)&wp2[0];
            bA1 = *(const short8*)&wp2[512];
        }
        __builtin_amdgcn_s_setprio(1);
#pragma unroll
        for(int mt=0; mt<4; mt++){
            short8 b = bh[mt];
            acc[0][mt] = __builtin_amdgcn_mfma_f32_16x16x32_bf16(bB0, b, acc[0][mt], 0, 0, 0);
            acc[1][mt] = __builtin_amdgcn_mfma_f32_16x16x32_bf16(bB1, b, acc[1][mt], 0, 0, 0);
            if(i2 < 3) bh[mt] = ld_h<ESTR>(hb, mt*16 + arow, (kt0+2)*32 + g*8);  // refill next pair
        }
        __builtin_amdgcn_s_setprio(0);
    }
    __syncthreads();   // all h1 reads done before overwrite

    // ---- h2 writeback ------------------------------------------------------
#pragma unroll
    for(int nt=0; nt<2; nt++)
#pragma unroll
        for(int mt=0; mt<4; mt++)
            st_h<ESTR>(hb, mt*16 + arow, w*32 + nt*16 + g*4, pack4(acc[nt][mt]));
    __syncthreads();

    // ---- layer 3: A/B W3 buffers + rotated bh refill -----------------------
    f32x4 acc3[2];
    acc3[0] = (f32x4){0.f,0.f,0.f,0.f};
    acc3[1] = (f32x4){0.f,0.f,0.f,0.f};

    short8 wA = *(const short8*)&w3base[0];
    short8 bh3[2];
#pragma unroll
    for(int i=0;i<2;i++) bh3[i] = ld_h<ESTR>(hb, (mh*2+i)*16 + arow, g*8);

#pragma unroll 1
    for(int i2=0; i2<4; i2++){
        const int kt0 = i2*2, kt1 = i2*2+1;
        short8 wB = *(const short8*)&w3base[kt1*2048];
        __builtin_amdgcn_s_setprio(1);
#pragma unroll
        for(int i=0;i<2;i++){
            short8 b = bh3[i];
            acc3[i] = __builtin_amdgcn_mfma_f32_16x16x32_bf16(wA, b, acc3[i], 0, 0, 0);
            bh3[i] = ld_h<ESTR>(hb, (mh*2+i)*16 + arow, kt1*32 + g*8);
        }
        __builtin_amdgcn_s_setprio(0);
        if(i2 < 3) wA = *(const short8*)&w3base[(kt0+2)*2048];
        __builtin_amdgcn_s_setprio(1);
#pragma unroll
        for(int i=0;i<2;i++){
            short8 b = bh3[i];
            acc3[i] = __builtin_amdgcn_mfma_f32_16x16x32_bf16(wB, b, acc3[i], 0, 0, 0);
            if(i2 < 3) bh3[i] = ld_h<ESTR>(hb, (mh*2+i)*16 + arow, (kt0+2)*32 + g*8);
        }
        __builtin_amdgcn_s_setprio(0);
    }

    // ---- epilogue: direct float4 stores (scale pre-folded) -----------------
    {
        int nc = nt3*16 + g*4;
#pragma unroll
        for(int i=0;i<2;i++){
            int mt = mh*2 + i;
            float4 o;
            o.x = acc3[i][0];
            o.y = acc3[i][1];
            o.z = acc3[i][2];
            o.w = acc3[i][3];
            *(float4*)&outy[(size_t)(m0 + mt*16 + arow)*80 + 16 + nc] = o;
        }
    }
}

// ---------------- aux path: 8 waves, wave w owns cols [w*16,w*16+16) -----------
__device__ __forceinline__ void aux_body(unsigned short* smem, int ab, int tid,
                                         const float* __restrict__ xs,
                                         const float* __restrict__ stats,
                                         const unsigned short* __restrict__ W1s,
                                         const float* __restrict__ b1p,
                                         const unsigned short* __restrict__ W2s,
                                         const float* __restrict__ ab2,
                                         const unsigned short* __restrict__ W3s,
                                         float* __restrict__ auxout){
    unsigned short* xa = smem;          // 1024 ushorts
    unsigned short* hb = smem + 1024;   // 64*ASTR ushorts, padded-linear

    const int w    = tid >> 6;
    const int lane = tid & 63;
    const int g    = lane >> 4;
    const int arow = lane & 15;
    const int k    = ab >> 6;
    const int b0   = (ab & 63) * 64;

    short8 w1r = {0,0,0,0,0,0,0,0};
    if(lane < 32) w1r = *(const short8*)&W1s[(size_t)k*2048 + (w*16 + arow)*16 + g*8];
    short8 w2r[4];
#pragma unroll
    for(int kt=0; kt<4; kt++)
        w2r[kt] = *(const short8*)&W2s[(size_t)k*16384 + kt*4096 + (w*16 + arow)*32 + g*8];
    short8 w3r[4];
#pragma unroll
    for(int kt=0; kt<4; kt++)
        w3r[kt] = *(const short8*)&W3s[(size_t)k*2048 + kt*512 + arow*32 + g*8];

    {
        const int c2  = (tid & 7)*2;
        const int r0p = tid >> 3;
        float2 v = *(const float2*)(xs + (size_t)(b0 + r0p)*(NTIME*NDIM) + c2);
        unsigned u = cvt_pk((v.x - stats[32+c2])*stats[48+c2],
                            (v.y - stats[32+c2+1])*stats[48+c2+1]);
        *(unsigned*)&xa[r0p*16 + c2] = u;
    }
    __syncthreads();

    {
        float4 b4 = *(const float4*)&b1p[k*128 + w*16 + g*4];
        f32x4 bi = {b4.x, b4.y, b4.z, b4.w};
#pragma unroll
        for(int mt=0; mt<4; mt++){
            short8 bx = {0,0,0,0,0,0,0,0};
            if(lane < 32) bx = *(const short8*)&xa[(mt*16 + arow)*16 + g*8];
            f32x4 a = __builtin_amdgcn_mfma_f32_16x16x32_bf16(w1r, bx, bi, 0, 0, 0);
            st_h<ASTR>(hb, mt*16 + arow, w*16 + g*4, pack4(a));
        }
    }
    __syncthreads();

    f32x4 acc2[4];
    {
        float4 b4 = *(const float4*)&ab2[k*128 + w*16 + g*4];
        f32x4 bi = {b4.x, b4.y, b4.z, b4.w};
#pragma unroll
        for(int m=0;m<4;m++) acc2[m] = bi;
    }
    __builtin_amdgcn_s_setprio(1);
#pragma unroll
    for(int kt=0; kt<4; kt++){
#pragma unroll
        for(int mt=0; mt<4; mt++){
            short8 bh = ld_h<ASTR>(hb, mt*16 + arow, kt*32 + g*8);
            acc2[mt] = __builtin_amdgcn_mfma_f32_16x16x32_bf16(w2r[kt], bh, acc2[mt], 0, 0, 0);
        }
    }
    __builtin_amdgcn_s_setprio(0);
    __syncthreads();

#pragma unroll
    for(int mt=0; mt<4; mt++)
        st_h<ASTR>(hb, mt*16 + arow, w*16 + g*4, pack4(acc2[mt]));
    __syncthreads();

    // layer 3: asc*DT pre-folded into W3s
    if(w < 4){
        f32x4 acc3 = {0.f,0.f,0.f,0.f};
#pragma unroll
        for(int kt=0; kt<4; kt++){
            short8 bh = ld_h<ASTR>(hb, w*16 + arow, kt*32 + g*8);
            acc3 = __builtin_amdgcn_mfma_f32_16x16x32_bf16(w3r[kt], bh, acc3, 0, 0, 0);
        }
        if(g == 0){
            float2 o;
            o.x = acc3[0];
            o.y = acc3[1];
            *(float2*)&auxout[(size_t)(b0 + w*16 + arow)*64 + 2*k] = o;
        }
    }
}

// ================= Mega-kernel 2: encoder MLP + aux MLP (512 threads) ==========
__global__ __launch_bounds__(512, 6) void k_mega2(const float* __restrict__ xs,
                                               const float* __restrict__ stats,
                                               const unsigned short* __restrict__ W1bf,
                                               const float* __restrict__ b1,
                                               const unsigned short* __restrict__ W2s,
                                               const float* __restrict__ b2,
                                               const unsigned short* __restrict__ W3s,
                                               const unsigned short* __restrict__ aW1s,
                                               const float* __restrict__ b1p,
                                               const unsigned short* __restrict__ aW2s,
                                               const float* __restrict__ ab2,
                                               const unsigned short* __restrict__ aW3s,
                                               float* __restrict__ outy,
                                               float* __restrict__ auxout){
    __shared__ unsigned short smem[1024 + 64*ESTR];   // ~35.8 KB, aliased
    const int blk = blockIdx.x;
    const int tid = threadIdx.x;
    if(blk < ENC_BLOCKS){
        enc_body(smem, blk, tid, xs, stats, W1bf, b1, W2s, b2, W3s, outy);
    } else {
        aux_body(smem, blk - ENC_BLOCKS, tid, xs, stats, aW1s, b1p, aW2s, ab2, aW3s, auxout);
    }
}

// ---------------- Kernel 5: closed-form scan -> y_pred -------------------------
__global__ __launch_bounds__(256) void k_pred(const float* __restrict__ xs,
                                              const float* __restrict__ auxbuf,
                                              const float* __restrict__ Cw,
                                              const float* __restrict__ outy,
                                              float* __restrict__ outyp){
    __shared__ float cw[16*64];
    const int tid = threadIdx.x;
    for(int j=tid; j<1024; j+=256) cw[j] = Cw[j];
    __syncthreads();

    int gid = blockIdx.x*256 + tid;
    int b = gid >> 6;
    int t = gid & 63;
    const float* yb = outy + (size_t)b*(NTIME*80) + 16;
    const float* ab = auxbuf + (size_t)b*64;
    float tt = (float)t;

    float y[64];
#pragma unroll
    for(int k=0;k<32;k++){
        float th0 = ab[2*k+0];
        float th1 = ab[2*k+1];
        float scl = __expf(th0*tt);
        float cc  = __cosf(th1*tt)*scl;
        float ss  = __sinf(th1*tt)*scl;
        float2 y01 = *(const float2*)&yb[2*k];
        y[2*k+0] = cc*y01.x - ss*y01.y;
        y[2*k+1] = ss*y01.x + cc*y01.y;
    }

    float* orow = outyp + (size_t)(b*NTIME + t)*80;
    if(t == 0){
        const float4* p = (const float4*)(xs + (size_t)b*(NTIME*NDIM));
#pragma unroll
        for(int i4=0;i4<4;i4++) *(float4*)&orow[i4*4] = p[i4];
    } else {
#pragma unroll
        for(int i4=0;i4<4;i4++){
            float o[4];
#pragma unroll
            for(int ii=0;ii<4;ii++){
                int i = i4*4+ii;
                float a = 0.f;
#pragma unroll
                for(int j4=0;j4<16;j4++){
                    float4 c4 = *(const float4*)&cw[i*64 + j4*4];
                    a += c4.x*y[j4*4+0] + c4.y*y[j4*4+1] + c4.z*y[j4*4+2] + c4.w*y[j4*4+3];
                }
                o[ii] = a;
            }
            *(float4*)&orow[i4*4] = make_float4(o[0],o[1],o[2],o[3]);
        }
    }
#pragma unroll
    for(int j4=0;j4<16;j4++){
        *(float4*)&orow[16+j4*4] = make_float4(y[j4*4+0],y[j4*4+1],y[j4*4+2],y[j4*4+3]);
    }
}

// ---------------- host launcher -----------------------------------------------
extern "C" void kernel_launch(void* const* d_in, const int* in_sizes, int n_in,
                              void* d_out, int out_size, void* d_ws, size_t ws_size,
                              hipStream_t stream) {
    const float* xs     = (const float*)d_in[0];
    const float* enc_g  = (const float*)d_in[1];
    const float* enc_bt = (const float*)d_in[2];
    const float* eW1    = (const float*)d_in[3];
    const float* eb1    = (const float*)d_in[4];
    const float* eW2    = (const float*)d_in[5];
    const float* eb2    = (const float*)d_in[6];
    const float* eW3    = (const float*)d_in[7];
    const float* esc    = (const float*)d_in[8];
    const float* ag     = (const float*)d_in[9];
    const float* abt    = (const float*)d_in[10];
    const float* aW1    = (const float*)d_in[11];
    const float* ab1    = (const float*)d_in[12];
    const float* aW2    = (const float*)d_in[13];
    const float* ab2    = (const float*)d_in[14];
    const float* aW3    = (const float*)d_in[15];
    const float* asc    = (const float*)d_in[16];
    const float* Cw     = (const float*)d_in[17];

    float* out   = (float*)d_out;
    float* ws    = (float*)d_ws;
    float* part   = ws;                  // 32768 floats (1024 x 32)
    float* stats  = ws + 32768;          // 64 floats
    float* part2  = ws + 32832;          // 512 floats
    float* auxout = ws + 33344;          // 262144 floats
    float* b1p    = ws + 295488;         // 4096 floats
    unsigned short* wbf = (unsigned short*)(ws + 299584);
    unsigned short* W1bf = wbf;           // 4096
    unsigned short* W2s  = wbf + 4096;    // 65536
    unsigned short* W3s  = wbf + 69632;   // 16384
    unsigned short* aW1s = wbf + 86016;   // 65536
    unsigned short* aW2s = wbf + 151552;  // 524288
    unsigned short* aW3s = wbf + 675840;  // 65536

    float* outy  = out;                            // (B,64,80)
    float* outyp = out + (size_t)NBATCH*NTIME*80;  // (B,64,80)

    k_mega1<<<3952, 256, 0, stream>>>(eW1, eW2, eW3, esc, ag, aW1, aW2, aW3, asc,
                                      ab1, abt, xs, wbf, b1p, part, part2);
    k_finalize<<<1, 256, 0, stream>>>(part, part2, enc_g, enc_bt, stats);
    k_mega2<<<ENC_BLOCKS + AUX_BLOCKS, 512, 0, stream>>>(
        xs, stats, W1bf, eb1, W2s, eb2, W3s,
        aW1s, b1p, aW2s, ab2, aW3s, outy, auxout);
    k_pred<<<MROWS/256, 256, 0, stream>>>(xs, auxout, Cw, outy, outyp);
}

// Round 18
// 133.922 us; speedup vs baseline: 1.0197x; 1.0197x over previous
//
#include <hip/hip_runtime.h>
#include <cstddef>

#define NBATCH 4096
#define NTIME  64
#define NDIM   16
#define NLDIM  64
#define NAUXK  32
#define NAH    128
#define NH     256
#define MROWS  (NBATCH*NTIME)   // 262144
#define DT_C   0.01f
#define EPS_C  1e-5f
#define ENC_BLOCKS (MROWS/64)              // 4096 (one 64-row tile per block)
#define AUX_BLOCKS (NAUXK*64)              // 2048
#define ESTR 264     // enc h stride (ushorts): 528B = 16 mod 128 -> bank-slot drift
#define ASTR 136     // aux h stride: 272B = 16 mod 128

using short8 = __attribute__((ext_vector_type(8))) short;
using short4v = __attribute__((ext_vector_type(4))) short;
using f32x4 = __attribute__((ext_vector_type(4))) float;

__device__ __forceinline__ float lrelu(float x){ return fmaxf(x, 0.01f*x); }
__device__ __forceinline__ unsigned short f2bf(float f){
    unsigned u = __builtin_bit_cast(unsigned, f);
    u += 0x7fff + ((u>>16)&1u);
    return (unsigned short)(u>>16);
}
// HW packed cvt: low16=bf16(a), high16=bf16(b), RNE
__device__ __forceinline__ unsigned cvt_pk(float a, float b){
    unsigned r;
    asm("v_cvt_pk_bf16_f32 %0, %1, %2" : "=v"(r) : "v"(a), "v"(b));
    return r;
}
__device__ __forceinline__ short4v pack4(f32x4 a){
    uint2 u;
    u.x = cvt_pk(lrelu(a[0]), lrelu(a[1]));
    u.y = cvt_pk(lrelu(a[2]), lrelu(a[3]));
    return __builtin_bit_cast(short4v, u);
}

// padded-linear LDS access: no swizzle, b128 reads, b64 writes
template<int STRIDE>
__device__ __forceinline__ short8 ld_h(const unsigned short* hb, int m, int c){
    return *(const short8*)&hb[m*STRIDE + c];
}
template<int STRIDE>
__device__ __forceinline__ void st_h(unsigned short* hb, int m, int c, short4v p){
    *(short4v*)&hb[m*STRIDE + c] = p;
}

// ================= Mega-kernel 1: prep + auxb fold + all partial stats =========
// blocks [0,2896): weight prep; [2896,2912): aux b1 fold;
// [2912,3936): enc BN partial stats (1024 blocks); [3936,3952): x0 partials.
__global__ __launch_bounds__(256) void k_mega1(const float* __restrict__ W1,
                                               const float* __restrict__ W2,
                                               const float* __restrict__ W3,
                                               const float* __restrict__ esc,
                                               const float* __restrict__ ag,
                                               const float* __restrict__ aW1,
                                               const float* __restrict__ aW2,
                                               const float* __restrict__ aW3,
                                               const float* __restrict__ asc,
                                               const float* __restrict__ ab1,
                                               const float* __restrict__ abt,
                                               const float* __restrict__ xs,
                                               unsigned short* __restrict__ dst,
                                               float* __restrict__ b1p,
                                               float* __restrict__ part,
                                               float* __restrict__ part2){
    __shared__ float red[256*33];
    const int blk = blockIdx.x;
    const int tid = threadIdx.x;

    if(blk < 2896){
        int i = blk*256 + tid;
        float v;
        if(i < 4096){ v = W1[i]; }
        else if(i < 69632){
            int e = i - 4096;
            int kt = e>>13, r = e&8191;
            int rb = r>>9, sft = r&511;
            int l = sft>>3, j = sft&7;
            int g = l>>4, arw = l&15;
            v = W2[(rb*16+arw)*256 + kt*32 + g*8 + j];
        } else if(i < 86016){
            int e = i - 69632;
            int kt = e>>11, r = e&2047;
            int rb = r>>9, sft = r&511;
            int l = sft>>3, j = sft&7;
            int g = l>>4, arw = l&15;
            int n = rb*16 + arw;
            v = W3[n*256 + kt*32 + g*8 + j] * esc[n];       // esc folded in
        } else if(i < 151552){
            int e = i - 86016; int k = e>>11, n = (e>>4)&127, c = e&15;
            v = aW1[(k*128+n)*16 + c] * ag[k*16+c];
        } else if(i < 675840){
            int e = i - 151552; int k = e>>14, kt = (e>>12)&3, n = (e>>5)&127, j = e&31;
            v = aW2[(k*128+n)*128 + kt*32 + j];
        } else if(i < 741376){
            int e = i - 675840; int k = e>>11, kt = (e>>9)&3, n = (e>>5)&15, j = e&31;
            v = (n < 2) ? aW3[(k*2+n)*128 + kt*32 + j] * asc[k*2+n] * DT_C : 0.f;  // asc*DT folded
        } else return;
        dst[i] = f2bf(v);
    } else if(blk < 2912){
        int i = (blk-2896)*256 + tid;
        int k = i>>7, n = i&127;
        const float* wr = aW1 + (size_t)(k*128+n)*16;
        const float* bt = abt + k*16;
        float a = ab1[i];
#pragma unroll
        for(int c=0;c<16;c++) a += wr[c]*bt[c];
        b1p[i] = a;
    } else if(blk < 3936){
        int sblk = blk - 2912;
        int r0 = sblk*256 + tid;
        const float4* p = (const float4*)(xs + (size_t)r0*NDIM);
        float s[16], q[16];
#pragma unroll
        for(int v=0; v<4; v++){
            float4 f = p[v];
            s[v*4+0]=f.x; q[v*4+0]=f.x*f.x;
            s[v*4+1]=f.y; q[v*4+1]=f.y*f.y;
            s[v*4+2]=f.z; q[v*4+2]=f.z*f.z;
            s[v*4+3]=f.w; q[v*4+3]=f.w*f.w;
        }
#pragma unroll
        for(int i=0;i<16;i++){ red[tid*33+i]=s[i]; red[tid*33+16+i]=q[i]; }
        __syncthreads();
        for(int off=128; off>0; off>>=1){
            if(tid < off){
#pragma unroll
                for(int i=0;i<32;i++) red[tid*33+i] += red[(tid+off)*33+i];
            }
            __syncthreads();
        }
        if(tid < 32) part[sblk*32 + tid] = red[tid];
    } else {
        int sblk = blk - 3936;
        int b = sblk*256 + tid;
        const float4* p = (const float4*)(xs + (size_t)b*(NTIME*NDIM));
#pragma unroll
        for(int v=0; v<4; v++){
            float4 f = p[v];
            red[tid*33 + v*4+0] = f.x; red[tid*33+16 + v*4+0] = f.x*f.x;
            red[tid*33 + v*4+1] = f.y; red[tid*33+16 + v*4+1] = f.y*f.y;
            red[tid*33 + v*4+2] = f.z; red[tid*33+16 + v*4+2] = f.z*f.z;
            red[tid*33 + v*4+3] = f.w; red[tid*33+16 + v*4+3] = f.w*f.w;
        }
        __syncthreads();
        for(int off=128; off>0; off>>=1){
            if(tid < off){
#pragma unroll
                for(int i=0;i<32;i++) red[tid*33+i] += red[(tid+off)*33+i];
            }
            __syncthreads();
        }
        if(tid < 32) part2[sblk*32 + tid] = red[tid];
    }
}

// ---------------- Kernel 2: finalize stats (pure reduction) --------------------
// stats layout: [0:16]=a_enc, [16:32]=b_enc, [32:48]=m0, [48:64]=istd0
__global__ __launch_bounds__(256) void k_finalize(const float* __restrict__ part,
                                                  const float* __restrict__ part2,
                                                  const float* __restrict__ gamma,
                                                  const float* __restrict__ beta,
                                                  float* __restrict__ stats){
    __shared__ float red[256*33];
    __shared__ float x0tot[32];
    int tid = threadIdx.x;
#pragma unroll
    for(int i=0;i<32;i++) red[tid*33+i] = (tid < 16) ? part2[tid*32+i] : 0.f;
    __syncthreads();
    for(int off=8; off>0; off>>=1){
        if(tid < off){
#pragma unroll
            for(int i=0;i<32;i++) red[tid*33+i] += red[(tid+off)*33+i];
        }
        __syncthreads();
    }
    if(tid < 32) x0tot[tid] = red[tid];
    __syncthreads();
#pragma unroll
    for(int i=0;i<32;i++){
        float a = part[tid*32+i] + part[(tid+256)*32+i]
                + part[(tid+512)*32+i] + part[(tid+768)*32+i];
        red[tid*33+i] = a;
    }
    __syncthreads();
    for(int off=128; off>0; off>>=1){
        if(tid < off){
#pragma unroll
            for(int i=0;i<32;i++) red[tid*33+i] += red[(tid+off)*33+i];
        }
        __syncthreads();
    }
    if(tid < 16){
        int i = tid;
        float m0 = x0tot[i] / (float)NBATCH;
        float v0 = x0tot[16+i] / (float)NBATCH - m0*m0;
        stats[32+i] = m0;
        stats[48+i] = 1.0f / sqrtf(v0 + EPS_C);
        float me = red[i] / (float)MROWS;
        float ve = red[16+i] / (float)MROWS - me*me;
        float a = gamma[i] / sqrtf(ve + EPS_C);
        stats[i]      = a;
        stats[16+i]   = beta[i] - me*a;
    }
}

// ---------------- enc path: 8 waves, wave w owns cols [w*32,w*32+32) -----------
__device__ __forceinline__ void enc_body(unsigned short* smem, int eb, int tid,
                                         const float* __restrict__ xs,
                                         const float* __restrict__ stats,
                                         const unsigned short* __restrict__ W1bf,
                                         const float* __restrict__ b1,
                                         const unsigned short* __restrict__ W2s,
                                         const float* __restrict__ b2,
                                         const unsigned short* __restrict__ W3s,
                                         float* __restrict__ outy){
    unsigned short* xa = smem;          // 1024 ushorts
    unsigned short* hb = smem + 1024;   // 64*ESTR ushorts, padded-linear

    const int w    = tid >> 6;          // 0..7
    const int lane = tid & 63;
    const int g    = lane >> 4;
    const int arow = lane & 15;
    const int mh   = w & 1;             // layer-3 row-half
    const int nt3  = w >> 1;            // layer-3 col-tile

    const int c2  = (tid & 7)*2;
    const int r0p = tid >> 3;
    const float sa0 = stats[c2],    sa1 = stats[c2+1];
    const float sb0 = stats[16+c2], sb1 = stats[16+c2+1];

    const unsigned short* w2base = W2s + (w*2)*512 + lane*8;  // rb = w*2+nt
    const unsigned short* w3base = W3s + nt3*512 + lane*8;    // rb = nt3

    const int m0 = eb*64;

    // prefetch W2 kt=0 into buffer A (hidden under phase0 + layer1)
    short8 bA0 = *(const short8*)&w2base[0];
    short8 bA1 = *(const short8*)&w2base[512];

    // ---- phase 0: 64 rows, passthrough + BN->bf16 (float2/thread) ---------
    {
        float2 v = *(const float2*)(xs + (size_t)(m0 + r0p)*NDIM + c2);
        *(float2*)(outy + (size_t)(m0 + r0p)*80 + c2) = v;
        unsigned u = cvt_pk(v.x*sa0 + sb0, v.y*sa1 + sb1);
        *(unsigned*)&xa[r0p*16 + c2] = u;
    }
    __syncthreads();

    // ---- layer 1: K=16; bias in MFMA C operand ----------------------------
#pragma unroll
    for(int nt=0; nt<2; nt++){
        short8 aw = {0,0,0,0,0,0,0,0};
        if(lane < 32) aw = *(const short8*)&W1bf[(w*32 + nt*16 + arow)*16 + g*8];
        float4 b4 = *(const float4*)&b1[w*32 + nt*16 + g*4];
        f32x4 bi = {b4.x, b4.y, b4.z, b4.w};
#pragma unroll
        for(int mt=0; mt<4; mt++){
            short8 bx = {0,0,0,0,0,0,0,0};
            if(lane < 32) bx = *(const short8*)&xa[(mt*16 + arow)*16 + g*8];
            f32x4 a = __builtin_amdgcn_mfma_f32_16x16x32_bf16(aw, bx, bi, 0, 0, 0);
            st_h<ESTR>(hb, mt*16 + arow, w*32 + nt*16 + g*4, pack4(a));
        }
    }
    __syncthreads();

    // ---- layer 2: K=256, alternating A/B W2 buffers -----------------------
    f32x4 acc[2][4];
#pragma unroll
    for(int nt=0; nt<2; nt++){
        float4 b4 = *(const float4*)&b2[w*32 + nt*16 + g*4];
        f32x4 bi = {b4.x, b4.y, b4.z, b4.w};
#pragma unroll
        for(int m=0;m<4;m++) acc[nt][m] = bi;
    }

#pragma unroll 1
    for(int i2=0; i2<4; i2++){
        const int kt0 = i2*2, kt1 = i2*2+1;
        const unsigned short* wp1 = w2base + kt1*8192;
        short8 bB0 = *(const short8*)&wp1[0];
        short8 bB1 = *(const short8*)&wp1[512];
        __builtin_amdgcn_s_setprio(1);
#pragma unroll
        for(int mt=0; mt<4; mt++){
            short8 bh = ld_h<ESTR>(hb, mt*16 + arow, kt0*32 + g*8);
            acc[0][mt] = __builtin_amdgcn_mfma_f32_16x16x32_bf16(bA0, bh, acc[0][mt], 0, 0, 0);
            acc[1][mt] = __builtin_amdgcn_mfma_f32_16x16x32_bf16(bA1, bh, acc[1][mt], 0, 0, 0);
        }
        __builtin_amdgcn_s_setprio(0);
        if(i2 < 3){
            const unsigned short* wp2 = w2base + (kt0+2)*8192;
            bA0 = *(const short8*)&wp2[0];
            bA1 = *(const short8*)&wp2[512];
        }
        __builtin_amdgcn_s_setprio(1);
#pragma unroll
        for(int mt=0; mt<4; mt++){
            short8 bh = ld_h<ESTR>(hb, mt*16 + arow, kt1*32 + g*8);
            acc[0][mt] = __builtin_amdgcn_mfma_f32_16x16x32_bf16(bB0, bh, acc[0][mt], 0, 0, 0);
            acc[1][mt] = __builtin_amdgcn_mfma_f32_16x16x32_bf16(bB1, bh, acc[1][mt], 0, 0, 0);
        }
        __builtin_amdgcn_s_setprio(0);
    }
    __syncthreads();   // all h1 reads done before overwrite

    // ---- h2 writeback ------------------------------------------------------
#pragma unroll
    for(int nt=0; nt<2; nt++)
#pragma unroll
        for(int mt=0; mt<4; mt++)
            st_h<ESTR>(hb, mt*16 + arow, w*32 + nt*16 + g*4, pack4(acc[nt][mt]));
    __syncthreads();

    // ---- layer 3: wave (nt3, mh): cols nt3*16.., rows [mh*32, mh*32+32) ----
    f32x4 acc3[2];
    acc3[0] = (f32x4){0.f,0.f,0.f,0.f};
    acc3[1] = (f32x4){0.f,0.f,0.f,0.f};
#pragma unroll 1
    for(int kt=0; kt<8; kt++){
        short8 aw3 = *(const short8*)&w3base[kt*2048];
        __builtin_amdgcn_s_setprio(1);
#pragma unroll
        for(int i=0;i<2;i++){
            int mt = mh*2 + i;
            short8 bh = ld_h<ESTR>(hb, mt*16 + arow, kt*32 + g*8);
            acc3[i] = __builtin_amdgcn_mfma_f32_16x16x32_bf16(aw3, bh, acc3[i], 0, 0, 0);
        }
        __builtin_amdgcn_s_setprio(0);
    }

    // ---- epilogue: direct float4 stores (scale pre-folded) -----------------
    {
        int nc = nt3*16 + g*4;
#pragma unroll
        for(int i=0;i<2;i++){
            int mt = mh*2 + i;
            float4 o;
            o.x = acc3[i][0];
            o.y = acc3[i][1];
            o.z = acc3[i][2];
            o.w = acc3[i][3];
            *(float4*)&outy[(size_t)(m0 + mt*16 + arow)*80 + 16 + nc] = o;
        }
    }
}

// ---------------- aux path: 8 waves, wave w owns cols [w*16,w*16+16) -----------
__device__ __forceinline__ void aux_body(unsigned short* smem, int ab, int tid,
                                         const float* __restrict__ xs,
                                         const float* __restrict__ stats,
                                         const unsigned short* __restrict__ W1s,
                                         const float* __restrict__ b1p,
                                         const unsigned short* __restrict__ W2s,
                                         const float* __restrict__ ab2,
                                         const unsigned short* __restrict__ W3s,
                                         float* __restrict__ auxout){
    unsigned short* xa = smem;          // 1024 ushorts
    unsigned short* hb = smem + 1024;   // 64*ASTR ushorts, padded-linear

    const int w    = tid >> 6;
    const int lane = tid & 63;
    const int g    = lane >> 4;
    const int arow = lane & 15;
    const int k    = ab >> 6;
    const int b0   = (ab & 63) * 64;

    short8 w1r = {0,0,0,0,0,0,0,0};
    if(lane < 32) w1r = *(const short8*)&W1s[(size_t)k*2048 + (w*16 + arow)*16 + g*8];
    short8 w2r[4];
#pragma unroll
    for(int kt=0; kt<4; kt++)
        w2r[kt] = *(const short8*)&W2s[(size_t)k*16384 + kt*4096 + (w*16 + arow)*32 + g*8];
    short8 w3r[4];
#pragma unroll
    for(int kt=0; kt<4; kt++)
        w3r[kt] = *(const short8*)&W3s[(size_t)k*2048 + kt*512 + arow*32 + g*8];

    {
        const int c2  = (tid & 7)*2;
        const int r0p = tid >> 3;
        float2 v = *(const float2*)(xs + (size_t)(b0 + r0p)*(NTIME*NDIM) + c2);
        unsigned u = cvt_pk((v.x - stats[32+c2])*stats[48+c2],
                            (v.y - stats[32+c2+1])*stats[48+c2+1]);
        *(unsigned*)&xa[r0p*16 + c2] = u;
    }
    __syncthreads();

    {
        float4 b4 = *(const float4*)&b1p[k*128 + w*16 + g*4];
        f32x4 bi = {b4.x, b4.y, b4.z, b4.w};
#pragma unroll
        for(int mt=0; mt<4; mt++){
            short8 bx = {0,0,0,0,0,0,0,0};
            if(lane < 32) bx = *(const short8*)&xa[(mt*16 + arow)*16 + g*8];
            f32x4 a = __builtin_amdgcn_mfma_f32_16x16x32_bf16(w1r, bx, bi, 0, 0, 0);
            st_h<ASTR>(hb, mt*16 + arow, w*16 + g*4, pack4(a));
        }
    }
    __syncthreads();

    f32x4 acc2[4];
    {
        float4 b4 = *(const float4*)&ab2[k*128 + w*16 + g*4];
        f32x4 bi = {b4.x, b4.y, b4.z, b4.w};
#pragma unroll
        for(int m=0;m<4;m++) acc2[m] = bi;
    }
    __builtin_amdgcn_s_setprio(1);
#pragma unroll
    for(int kt=0; kt<4; kt++){
#pragma unroll
        for(int mt=0; mt<4; mt++){
            short8 bh = ld_h<ASTR>(hb, mt*16 + arow, kt*32 + g*8);
            acc2[mt] = __builtin_amdgcn_mfma_f32_16x16x32_bf16(w2r[kt], bh, acc2[mt], 0, 0, 0);
        }
    }
    __builtin_amdgcn_s_setprio(0);
    __syncthreads();

#pragma unroll
    for(int mt=0; mt<4; mt++)
        st_h<ASTR>(hb, mt*16 + arow, w*16 + g*4, pack4(acc2[mt]));
    __syncthreads();

    // layer 3: asc*DT pre-folded into W3s
    if(w < 4){
        f32x4 acc3 = {0.f,0.f,0.f,0.f};
#pragma unroll
        for(int kt=0; kt<4; kt++){
            short8 bh = ld_h<ASTR>(hb, w*16 + arow, kt*32 + g*8);
            acc3 = __builtin_amdgcn_mfma_f32_16x16x32_bf16(w3r[kt], bh, acc3, 0, 0, 0);
        }
        if(g == 0){
            float2 o;
            o.x = acc3[0];
            o.y = acc3[1];
            *(float2*)&auxout[(size_t)(b0 + w*16 + arow)*64 + 2*k] = o;
        }
    }
}

// ================= Mega-kernel 2: encoder MLP + aux MLP (512 threads) ==========
__global__ __launch_bounds__(512, 8) void k_mega2(const float* __restrict__ xs,
                                               const float* __restrict__ stats,
                                               const unsigned short* __restrict__ W1bf,
                                               const float* __restrict__ b1,
                                               const unsigned short* __restrict__ W2s,
                                               const float* __restrict__ b2,
                                               const unsigned short* __restrict__ W3s,
                                               const unsigned short* __restrict__ aW1s,
                                               const float* __restrict__ b1p,
                                               const unsigned short* __restrict__ aW2s,
                                               const float* __restrict__ ab2,
                                               const unsigned short* __restrict__ aW3s,
                                               float* __restrict__ outy,
                                               float* __restrict__ auxout){
    __shared__ unsigned short smem[1024 + 64*ESTR];   // ~35.8 KB, aliased
    const int blk = blockIdx.x;
    const int tid = threadIdx.x;
    if(blk < ENC_BLOCKS){
        enc_body(smem, blk, tid, xs, stats, W1bf, b1, W2s, b2, W3s, outy);
    } else {
        aux_body(smem, blk - ENC_BLOCKS, tid, xs, stats, aW1s, b1p, aW2s, ab2, aW3s, auxout);
    }
}

// ---------------- Kernel 5: closed-form scan -> y_pred -------------------------
__global__ __launch_bounds__(256) void k_pred(const float* __restrict__ xs,
                                              const float* __restrict__ auxbuf,
                                              const float* __restrict__ Cw,
                                              const float* __restrict__ outy,
                                              float* __restrict__ outyp){
    __shared__ float cw[16*64];
    const int tid = threadIdx.x;
    for(int j=tid; j<1024; j+=256) cw[j] = Cw[j];
    __syncthreads();

    int gid = blockIdx.x*256 + tid;
    int b = gid >> 6;
    int t = gid & 63;
    const float* yb = outy + (size_t)b*(NTIME*80) + 16;
    const float* ab = auxbuf + (size_t)b*64;
    float tt = (float)t;

    float y[64];
#pragma unroll
    for(int k=0;k<32;k++){
        float th0 = ab[2*k+0];
        float th1 = ab[2*k+1];
        float scl = __expf(th0*tt);
        float cc  = __cosf(th1*tt)*scl;
        float ss  = __sinf(th1*tt)*scl;
        float2 y01 = *(const float2*)&yb[2*k];
        y[2*k+0] = cc*y01.x - ss*y01.y;
        y[2*k+1] = ss*y01.x + cc*y01.y;
    }

    float* orow = outyp + (size_t)(b*NTIME + t)*80;
    if(t == 0){
        const float4* p = (const float4*)(xs + (size_t)b*(NTIME*NDIM));
#pragma unroll
        for(int i4=0;i4<4;i4++) *(float4*)&orow[i4*4] = p[i4];
    } else {
#pragma unroll
        for(int i4=0;i4<4;i4++){
            float o[4];
#pragma unroll
            for(int ii=0;ii<4;ii++){
                int i = i4*4+ii;
                float a = 0.f;
#pragma unroll
                for(int j4=0;j4<16;j4++){
                    float4 c4 = *(const float4*)&cw[i*64 + j4*4];
                    a += c4.x*y[j4*4+0] + c4.y*y[j4*4+1] + c4.z*y[j4*4+2] + c4.w*y[j4*4+3];
                }
                o[ii] = a;
            }
            *(float4*)&orow[i4*4] = make_float4(o[0],o[1],o[2],o[3]);
        }
    }
#pragma unroll
    for(int j4=0;j4<16;j4++){
        *(float4*)&orow[16+j4*4] = make_float4(y[j4*4+0],y[j4*4+1],y[j4*4+2],y[j4*4+3]);
    }
}

// ---------------- host launcher -----------------------------------------------
extern "C" void kernel_launch(void* const* d_in, const int* in_sizes, int n_in,
                              void* d_out, int out_size, void* d_ws, size_t ws_size,
                              hipStream_t stream) {
    const float* xs     = (const float*)d_in[0];
    const float* enc_g  = (const float*)d_in[1];
    const float* enc_bt = (const float*)d_in[2];
    const float* eW1    = (const float*)d_in[3];
    const float* eb1    = (const float*)d_in[4];
    const float* eW2    = (const float*)d_in[5];
    const float* eb2    = (const float*)d_in[6];
    const float* eW3    = (const float*)d_in[7];
    const float* esc    = (const float*)d_in[8];
    const float* ag     = (const float*)d_in[9];
    const float* abt    = (const float*)d_in[10];
    const float* aW1    = (const float*)d_in[11];
    const float* ab1    = (const float*)d_in[12];
    const float* aW2    = (const float*)d_in[13];
    const float* ab2    = (const float*)d_in[14];
    const float* aW3    = (const float*)d_in[15];
    const float* asc    = (const float*)d_in[16];
    const float* Cw     = (const float*)d_in[17];

    float* out   = (float*)d_out;
    float* ws    = (float*)d_ws;
    float* part   = ws;                  // 32768 floats (1024 x 32)
    float* stats  = ws + 32768;          // 64 floats
    float* part2  = ws + 32832;          // 512 floats
    float* auxout = ws + 33344;          // 262144 floats
    float* b1p    = ws + 295488;         // 4096 floats
    unsigned short* wbf = (unsigned short*)(ws + 299584);
    unsigned short* W1bf = wbf;           // 4096
    unsigned short* W2s  = wbf + 4096;    // 65536
    unsigned short* W3s  = wbf + 69632;   // 16384
    unsigned short* aW1s = wbf + 86016;   // 65536
    unsigned short* aW2s = wbf + 151552;  // 524288
    unsigned short* aW3s = wbf + 675840;  // 65536

    float* outy  = out;                            // (B,64,80)
    float* outyp = out + (size_t)NBATCH*NTIME*80;  // (B,64,80)

    k_mega1<<<3952, 256, 0, stream>>>(eW1, eW2, eW3, esc, ag, aW1, aW2, aW3, asc,
                                      ab1, abt, xs, wbf, b1p, part, part2);
    k_finalize<<<1, 256, 0, stream>>>(part, part2, enc_g, enc_bt, stats);
    k_mega2<<<ENC_BLOCKS + AUX_BLOCKS, 512, 0, stream>>>(
        xs, stats, W1bf, eb1, W2s, eb2, W3s,
        aW1s, b1p, aW2s, ab2, aW3s, outy, auxout);
    k_pred<<<MROWS/256, 256, 0, stream>>>(xs, auxout, Cw, outy, outyp);
}